// Round 1
// baseline (1312.796 us; speedup 1.0000x reference)
//
#include <hip/hip_runtime.h>
#include <math.h>

#define Nn 120000
#define Kk 8
#define Dd 64
#define Mm 100000
#define Pp 16
#define HGg 32
#define HDd 96

__device__ __forceinline__ float sigmoidf_(float x) { return 1.f / (1.f + __expf(-x)); }
__device__ __forceinline__ float tanh_fast(float x) {
    float e = __expf(2.f * x);          // inf for big x -> 1; 0 for very neg -> -1
    return 1.f - 2.f / (e + 1.f);
}

// dot of a 64-elem register array with a wave-uniform weight row (scalar loads)
__device__ __forceinline__ float dot64(const float* v, const float* __restrict__ w) {
    float s0 = 0.f, s1 = 0.f, s2 = 0.f, s3 = 0.f;
#pragma unroll
    for (int i = 0; i < 64; i += 4) {
        s0 = fmaf(v[i], w[i], s0);
        s1 = fmaf(v[i + 1], w[i + 1], s1);
        s2 = fmaf(v[i + 2], w[i + 2], s2);
        s3 = fmaf(v[i + 3], w[i + 3], s3);
    }
    return (s0 + s1) + (s2 + s3);
}

__device__ __forceinline__ float dot96(const float* v, const float* __restrict__ w) {
    float s0 = 0.f, s1 = 0.f, s2 = 0.f, s3 = 0.f;
#pragma unroll
    for (int i = 0; i < 96; i += 4) {
        s0 = fmaf(v[i], w[i], s0);
        s1 = fmaf(v[i + 1], w[i + 1], s1);
        s2 = fmaf(v[i + 2], w[i + 2], s2);
        s3 = fmaf(v[i + 3], w[i + 3], s3);
    }
    return (s0 + s1) + (s2 + s3);
}

// K0: Zall[m] = normalize(z_latent[m] @ Wz.T)   (M,16)
__global__ __launch_bounds__(256) void k0_projz(const float* __restrict__ z,
                                                const float* __restrict__ Wz,
                                                float* __restrict__ Zall) {
    int m = blockIdx.x * 256 + threadIdx.x;
    if (m >= Mm) return;
    const float4* zr = (const float4*)(z + (size_t)m * Dd);
    float acc[Pp];
#pragma unroll
    for (int p = 0; p < Pp; p++) acc[p] = 0.f;
    for (int d4 = 0; d4 < 16; ++d4) {
        float4 f4 = zr[d4];
#pragma unroll
        for (int p = 0; p < Pp; p++) {
            const float* w = Wz + p * Dd + d4 * 4;   // wave-uniform -> s_load
            acc[p] = fmaf(f4.x, w[0], acc[p]);
            acc[p] = fmaf(f4.y, w[1], acc[p]);
            acc[p] = fmaf(f4.z, w[2], acc[p]);
            acc[p] = fmaf(f4.w, w[3], acc[p]);
        }
    }
    float ss = 0.f;
#pragma unroll
    for (int p = 0; p < Pp; p++) ss = fmaf(acc[p], acc[p], ss);
    float inv = 1.f / (sqrtf(ss) + 1e-6f);
    float4* o = (float4*)(Zall + (size_t)m * Pp);
#pragma unroll
    for (int q = 0; q < 4; q++) {
        float4 v;
        v.x = acc[4 * q] * inv;
        v.y = acc[4 * q + 1] * inv;
        v.z = acc[4 * q + 2] * inv;
        v.w = acc[4 * q + 3] * inv;
        o[q] = v;
    }
}

// K1: per point: hash->searchsorted->vals atomic; Fp; sims; softmax -> wbuf
__global__ __launch_bounds__(256) void k1_route(const float* __restrict__ pts,
                                                const float* __restrict__ f_pts,
                                                const float* __restrict__ centers,
                                                const float* __restrict__ Wf,
                                                const float* __restrict__ w_delta,
                                                const float* __restrict__ b_delta,
                                                const float* __restrict__ log_temp,
                                                const int* __restrict__ keys,
                                                const int* __restrict__ cand,
                                                const float* __restrict__ Zall,
                                                float* __restrict__ wbuf,
                                                float* __restrict__ vacc) {
    int n = blockIdx.x * 256 + threadIdx.x;
    if (n >= Nn) return;
    float px = pts[3 * n], py = pts[3 * n + 1], pz = pts[3 * n + 2];
    // IEEE f32 divide then floor, matching the reference exactly (boundary-sensitive)
    int ix = (int)floorf(px / 0.1f);
    int iy = (int)floorf(py / 0.1f);
    int iz = (int)floorf(pz / 0.1f);
    int h = ((ix + 512) << 20) ^ ((iy + 512) << 10) ^ (iz + 512);
    // lower_bound (searchsorted side='left')
    int lo = 0, hi = Mm;
    while (lo < hi) {
        int mid = (lo + hi) >> 1;
        if (keys[mid] < h) lo = mid + 1; else hi = mid;
    }
    int vi = lo < (Mm - 1) ? lo : (Mm - 1);
    atomicAdd(vacc + vi, 0.5f);

    // Fp = normalize(f_pts[n] @ Wf.T)
    float acc[Pp];
#pragma unroll
    for (int p = 0; p < Pp; p++) acc[p] = 0.f;
    const float4* fr = (const float4*)(f_pts + (size_t)n * Dd);
    for (int d4 = 0; d4 < 16; ++d4) {
        float4 f4 = fr[d4];
#pragma unroll
        for (int p = 0; p < Pp; p++) {
            const float* w = Wf + p * Dd + d4 * 4;
            acc[p] = fmaf(f4.x, w[0], acc[p]);
            acc[p] = fmaf(f4.y, w[1], acc[p]);
            acc[p] = fmaf(f4.z, w[2], acc[p]);
            acc[p] = fmaf(f4.w, w[3], acc[p]);
        }
    }
    float ss = 0.f;
#pragma unroll
    for (int p = 0; p < Pp; p++) ss = fmaf(acc[p], acc[p], ss);
    float inv = 1.f / (sqrtf(ss) + 1e-6f);
#pragma unroll
    for (int p = 0; p < Pp; p++) acc[p] *= inv;

    float et = expf(log_temp[0]);
    float wdx = w_delta[0], wdy = w_delta[1], wdz = w_delta[2], bdl = b_delta[0];
    float sims[Kk];
#pragma unroll
    for (int k = 0; k < Kk; k++) {
        int id = cand[(size_t)n * Kk + k];
        const float4* zp = (const float4*)(Zall + (size_t)id * Pp);
        float core = 0.f;
#pragma unroll
        for (int q = 0; q < 4; q++) {
            float4 zv = zp[q];
            core = fmaf(acc[4 * q], zv.x, core);
            core = fmaf(acc[4 * q + 1], zv.y, core);
            core = fmaf(acc[4 * q + 2], zv.z, core);
            core = fmaf(acc[4 * q + 3], zv.w, core);
        }
        float cx = centers[3 * id], cy = centers[3 * id + 1], cz = centers[3 * id + 2];
        float dt = (px - cx) * wdx + (py - cy) * wdy + (pz - cz) * wdz + bdl;
        sims[k] = et * (core + dt);
    }
    // softmax(sims / TAU)
    float mx = -1e30f;
#pragma unroll
    for (int k = 0; k < Kk; k++) {
        sims[k] = sims[k] / 0.3f;
        mx = fmaxf(mx, sims[k]);
    }
    float e[Kk];
    float se = 0.f;
#pragma unroll
    for (int k = 0; k < Kk; k++) {
        e[k] = __expf(sims[k] - mx);
        se += e[k];
    }
    float isum = 1.f / se;
#pragma unroll
    for (int k = 0; k < Kk; k++) wbuf[(size_t)n * Kk + k] = e[k] * isum;
}

// K2: scatter w*f to msg, w to wsum. Wave per point, lane = feature dim.
// Each atomic instruction covers one contiguous 256B msg row.
__global__ __launch_bounds__(256) void k2_scatter(const float* __restrict__ f_pts,
                                                  const float* __restrict__ wbuf,
                                                  const int* __restrict__ cand,
                                                  float* __restrict__ msg,
                                                  float* __restrict__ wsum) {
    int wave = threadIdx.x >> 6;
    int lane = threadIdx.x & 63;
    int n = blockIdx.x * 4 + wave;          // grid = N/4 exactly
    float f = f_pts[(size_t)n * Dd + lane];
    int k8 = lane & 7;
    float wk = wbuf[(size_t)n * Kk + k8];
    int idxk = cand[(size_t)n * Kk + k8];
#pragma unroll
    for (int k = 0; k < Kk; k++) {
        float wv = __shfl(wk, k, 64);
        int id = __shfl(idxk, k, 64);
        atomicAdd(msg + (size_t)id * Dd + lane, wv * f);
    }
    if (lane < Kk) atomicAdd(wsum + idxk, wk);
}

// K3: per voxel: msg norm, gate MLP, GRU, LN, decoder MLP -> p; clip vals.
// Thread per voxel; weights via wave-uniform scalar loads; LDS scratch stripe
// (stride 97 words -> conflict-free) for dynamically-indexed z_new / hd1.
__global__ __launch_bounds__(128) void k3_voxel(const float* __restrict__ z_latent,
                                                const float* __restrict__ msg,
                                                const float* __restrict__ wsum,
                                                const float* __restrict__ Wg1,
                                                const float* __restrict__ bg1,
                                                const float* __restrict__ Wg2,
                                                const float* __restrict__ bg2,
                                                const float* __restrict__ W_ih,
                                                const float* __restrict__ W_hh,
                                                const float* __restrict__ b_ih,
                                                const float* __restrict__ b_hh,
                                                const float* __restrict__ ln_g,
                                                const float* __restrict__ ln_b,
                                                const float* __restrict__ Wd1,
                                                const float* __restrict__ bd1,
                                                const float* __restrict__ Wd2,
                                                const float* __restrict__ bd2,
                                                const float* __restrict__ Wd3,
                                                const float* __restrict__ bd3,
                                                const float* __restrict__ vacc,
                                                float* __restrict__ out) {
    __shared__ float sc[128 * 97];
    int m = blockIdx.x * 128 + threadIdx.x;
    if (m >= Mm) return;                    // no barriers in this kernel
    float* my = sc + threadIdx.x * 97;

    float z[Dd], mg[Dd];
    const float4* zr = (const float4*)(z_latent + (size_t)m * Dd);
    const float4* mr = (const float4*)(msg + (size_t)m * Dd);
    float minv = 1.f / (wsum[m] + 1e-6f);
#pragma unroll
    for (int i = 0; i < 16; i++) {
        float4 a = zr[i];
        z[4 * i] = a.x; z[4 * i + 1] = a.y; z[4 * i + 2] = a.z; z[4 * i + 3] = a.w;
        float4 b = mr[i];
        mg[4 * i] = b.x * minv; mg[4 * i + 1] = b.y * minv;
        mg[4 * i + 2] = b.z * minv; mg[4 * i + 3] = b.w * minv;
    }

    // gate: g = sigmoid(relu([z,mg] @ Wg1.T + bg1) @ Wg2.T + bg2)
    float ga = bg2[0];
    for (int j = 0; j < HGg; j++) {
        const float* wr = Wg1 + j * 2 * Dd;
        float a = bg1[j] + dot64(z, wr) + dot64(mg, wr + Dd);
        ga += fmaxf(a, 0.f) * Wg2[j];
    }
    float g = sigmoidf_(ga);

    // GRU; z_new -> LDS scratch; LN stats on the fly
    float ssum = 0.f, ssq = 0.f;
    for (int o = 0; o < Dd; o++) {
        float air = dot64(mg, W_ih + (size_t)o * Dd) + b_ih[o];
        float aiz = dot64(mg, W_ih + (size_t)(Dd + o) * Dd) + b_ih[Dd + o];
        float ain = dot64(mg, W_ih + (size_t)(2 * Dd + o) * Dd) + b_ih[2 * Dd + o];
        float ahr = dot64(z, W_hh + (size_t)o * Dd) + b_hh[o];
        float ahz = dot64(z, W_hh + (size_t)(Dd + o) * Dd) + b_hh[Dd + o];
        float ahn = dot64(z, W_hh + (size_t)(2 * Dd + o) * Dd) + b_hh[2 * Dd + o];
        float r = sigmoidf_(air + ahr);
        float u = sigmoidf_(aiz + ahz);
        float nn = tanh_fast(ain + r * ahn);
        float zo = z_latent[(size_t)m * Dd + o];   // L1-hot reload (dynamic index)
        float hn = (1.f - u) * nn + u * zo;
        float zn = zo + g * (hn - zo);
        my[o] = zn;
        ssum += zn;
        ssq = fmaf(zn, zn, ssq);
    }
    float mu = ssum * (1.f / 64.f);
    float var = ssq * (1.f / 64.f) - mu * mu;
    float rs = rsqrtf(var + 1e-5f);

    // LN -> x (registers, const-indexed)
    float x[Dd];
#pragma unroll
    for (int o = 0; o < Dd; o++) x[o] = (my[o] - mu) * rs * ln_g[o] + ln_b[o];

    // fc1 -> hd1 into LDS scratch (overwrites z_new region; x already extracted)
    for (int j = 0; j < HDd; j++) {
        float a = bd1[j] + dot64(x, Wd1 + (size_t)j * Dd);
        my[j] = fmaxf(a, 0.f);
    }
    // reload hd1 into const-indexed regs for the 96x96 matmul
    float h1[HDd];
#pragma unroll
    for (int j = 0; j < HDd; j++) h1[j] = my[j];

    float pa = bd3[0];
    for (int j = 0; j < HDd; j++) {
        float t = fmaxf(bd2[j] + dot96(h1, Wd2 + (size_t)j * HDd), 0.f);
        pa += (my[j] + t) * Wd3[j];    // hd2[j] = hd1[j] + relu(...)
    }
    float p = sigmoidf_(pa);
    out[m] = p;
    float v = vacc[m];
    out[Mm + m] = fminf(fmaxf(v, -2.f), 3.5f);
}

extern "C" void kernel_launch(void* const* d_in, const int* in_sizes, int n_in,
                              void* d_out, int out_size, void* d_ws, size_t ws_size,
                              hipStream_t stream) {
    const float* pts      = (const float*)d_in[0];
    const float* f_pts    = (const float*)d_in[1];
    const float* z_lat    = (const float*)d_in[2];
    const float* vals     = (const float*)d_in[3];
    const float* centers  = (const float*)d_in[4];
    const float* Wf       = (const float*)d_in[5];
    const float* Wz       = (const float*)d_in[6];
    const float* w_delta  = (const float*)d_in[7];
    const float* b_delta  = (const float*)d_in[8];
    const float* log_temp = (const float*)d_in[9];
    const float* W_ih     = (const float*)d_in[10];
    const float* W_hh     = (const float*)d_in[11];
    const float* b_ih     = (const float*)d_in[12];
    const float* b_hh     = (const float*)d_in[13];
    const float* Wg1      = (const float*)d_in[14];
    const float* bg1      = (const float*)d_in[15];
    const float* Wg2      = (const float*)d_in[16];
    const float* bg2      = (const float*)d_in[17];
    const float* ln_g     = (const float*)d_in[18];
    const float* ln_b     = (const float*)d_in[19];
    const float* Wd1      = (const float*)d_in[20];
    const float* bd1      = (const float*)d_in[21];
    const float* Wd2      = (const float*)d_in[22];
    const float* bd2      = (const float*)d_in[23];
    const float* Wd3      = (const float*)d_in[24];
    const float* bd3      = (const float*)d_in[25];
    const int*   keys     = (const int*)d_in[26];
    const int*   cand     = (const int*)d_in[27];
    float* out = (float*)d_out;

    float* ws   = (float*)d_ws;
    float* Zall = ws;                            // M*16
    float* wbuf = Zall + (size_t)Mm * Pp;        // N*8
    float* msg  = wbuf + (size_t)Nn * Kk;        // M*64
    float* wsum = msg + (size_t)Mm * Dd;         // M
    float* vacc = wsum + Mm;                     // M   (total ~36.6 MB)

    // zero msg+wsum (contiguous); seed vals accumulator from vals_st
    hipMemsetAsync(msg, 0, sizeof(float) * ((size_t)Mm * Dd + Mm), stream);
    hipMemcpyAsync(vacc, vals, sizeof(float) * Mm, hipMemcpyDeviceToDevice, stream);

    k0_projz<<<(Mm + 255) / 256, 256, 0, stream>>>(z_lat, Wz, Zall);
    k1_route<<<(Nn + 255) / 256, 256, 0, stream>>>(pts, f_pts, centers, Wf, w_delta,
                                                   b_delta, log_temp, keys, cand,
                                                   Zall, wbuf, vacc);
    k2_scatter<<<Nn / 4, 256, 0, stream>>>(f_pts, wbuf, cand, msg, wsum);
    k3_voxel<<<(Mm + 127) / 128, 128, 0, stream>>>(z_lat, msg, wsum, Wg1, bg1, Wg2, bg2,
                                                   W_ih, W_hh, b_ih, b_hh, ln_g, ln_b,
                                                   Wd1, bd1, Wd2, bd2, Wd3, bd3,
                                                   vacc, out);
}

// Round 2
// 518.571 us; speedup vs baseline: 2.5316x; 2.5316x over previous
//
#include <hip/hip_runtime.h>
#include <math.h>

#define Nn 120000
#define Kk 8
#define Dd 64
#define Mm 100000
#define Pp 16
#define HGg 32
#define HDd 96

typedef __attribute__((ext_vector_type(8))) short bf16x8;
typedef __attribute__((ext_vector_type(4))) float f32x4;

__device__ __forceinline__ float sigmoidf_(float x) { return 1.f / (1.f + __expf(-x)); }
__device__ __forceinline__ float tanh_fast(float x) {
    float e = __expf(2.f * x);          // inf for big x -> 1; 0 for very neg -> -1
    return 1.f - 2.f / (e + 1.f);
}
// f32 -> bf16 round-to-nearest-even
__device__ __forceinline__ short f2bf(float f) {
    unsigned u = __float_as_uint(f);
    unsigned r = (u + 0x7fffu + ((u >> 16) & 1u)) >> 16;
    return (short)r;
}

// ---------------- K0: Zall[m] = normalize(z_latent[m] @ Wz.T)  (M,16) -------
__global__ __launch_bounds__(256) void k0_projz(const float* __restrict__ z,
                                                const float* __restrict__ Wz,
                                                float* __restrict__ Zall) {
    int m = blockIdx.x * 256 + threadIdx.x;
    if (m >= Mm) return;
    const float4* zr = (const float4*)(z + (size_t)m * Dd);
    float acc[Pp];
#pragma unroll
    for (int p = 0; p < Pp; p++) acc[p] = 0.f;
    for (int d4 = 0; d4 < 16; ++d4) {
        float4 f4 = zr[d4];
#pragma unroll
        for (int p = 0; p < Pp; p++) {
            const float* w = Wz + p * Dd + d4 * 4;   // wave-uniform -> s_load
            acc[p] = fmaf(f4.x, w[0], acc[p]);
            acc[p] = fmaf(f4.y, w[1], acc[p]);
            acc[p] = fmaf(f4.z, w[2], acc[p]);
            acc[p] = fmaf(f4.w, w[3], acc[p]);
        }
    }
    float ss = 0.f;
#pragma unroll
    for (int p = 0; p < Pp; p++) ss = fmaf(acc[p], acc[p], ss);
    float inv = 1.f / (sqrtf(ss) + 1e-6f);
    float4* o = (float4*)(Zall + (size_t)m * Pp);
#pragma unroll
    for (int q = 0; q < 4; q++) {
        float4 v;
        v.x = acc[4 * q] * inv;
        v.y = acc[4 * q + 1] * inv;
        v.z = acc[4 * q + 2] * inv;
        v.w = acc[4 * q + 3] * inv;
        o[q] = v;
    }
}

// ---------------- K1: hash + searchsorted + vals atomic; routing softmax ----
__global__ __launch_bounds__(256) void k1_route(const float* __restrict__ pts,
                                                const float* __restrict__ f_pts,
                                                const float* __restrict__ centers,
                                                const float* __restrict__ Wf,
                                                const float* __restrict__ w_delta,
                                                const float* __restrict__ b_delta,
                                                const float* __restrict__ log_temp,
                                                const int* __restrict__ keys,
                                                const int* __restrict__ cand,
                                                const float* __restrict__ Zall,
                                                float* __restrict__ wbuf,
                                                float* __restrict__ vacc) {
    int n = blockIdx.x * 256 + threadIdx.x;
    if (n >= Nn) return;
    float px = pts[3 * n], py = pts[3 * n + 1], pz = pts[3 * n + 2];
    // IEEE f32 divide then floor, matching the reference exactly (boundary-sensitive)
    int ix = (int)floorf(px / 0.1f);
    int iy = (int)floorf(py / 0.1f);
    int iz = (int)floorf(pz / 0.1f);
    int h = ((ix + 512) << 20) ^ ((iy + 512) << 10) ^ (iz + 512);
    // lower_bound (searchsorted side='left')
    int lo = 0, hi = Mm;
    while (lo < hi) {
        int mid = (lo + hi) >> 1;
        if (keys[mid] < h) lo = mid + 1; else hi = mid;
    }
    int vi = lo < (Mm - 1) ? lo : (Mm - 1);
    atomicAdd(vacc + vi, 0.5f);

    // Fp = normalize(f_pts[n] @ Wf.T)
    float acc[Pp];
#pragma unroll
    for (int p = 0; p < Pp; p++) acc[p] = 0.f;
    const float4* fr = (const float4*)(f_pts + (size_t)n * Dd);
    for (int d4 = 0; d4 < 16; ++d4) {
        float4 f4 = fr[d4];
#pragma unroll
        for (int p = 0; p < Pp; p++) {
            const float* w = Wf + p * Dd + d4 * 4;
            acc[p] = fmaf(f4.x, w[0], acc[p]);
            acc[p] = fmaf(f4.y, w[1], acc[p]);
            acc[p] = fmaf(f4.z, w[2], acc[p]);
            acc[p] = fmaf(f4.w, w[3], acc[p]);
        }
    }
    float ss = 0.f;
#pragma unroll
    for (int p = 0; p < Pp; p++) ss = fmaf(acc[p], acc[p], ss);
    float inv = 1.f / (sqrtf(ss) + 1e-6f);
#pragma unroll
    for (int p = 0; p < Pp; p++) acc[p] *= inv;

    float et = expf(log_temp[0]);
    float wdx = w_delta[0], wdy = w_delta[1], wdz = w_delta[2], bdl = b_delta[0];
    float sims[Kk];
#pragma unroll
    for (int k = 0; k < Kk; k++) {
        int id = cand[(size_t)n * Kk + k];
        const float4* zp = (const float4*)(Zall + (size_t)id * Pp);
        float core = 0.f;
#pragma unroll
        for (int q = 0; q < 4; q++) {
            float4 zv = zp[q];
            core = fmaf(acc[4 * q], zv.x, core);
            core = fmaf(acc[4 * q + 1], zv.y, core);
            core = fmaf(acc[4 * q + 2], zv.z, core);
            core = fmaf(acc[4 * q + 3], zv.w, core);
        }
        float cx = centers[3 * id], cy = centers[3 * id + 1], cz = centers[3 * id + 2];
        float dt = (px - cx) * wdx + (py - cy) * wdy + (pz - cz) * wdz + bdl;
        sims[k] = et * (core + dt);
    }
    float mx = -1e30f;
#pragma unroll
    for (int k = 0; k < Kk; k++) {
        sims[k] = sims[k] / 0.3f;
        mx = fmaxf(mx, sims[k]);
    }
    float e[Kk];
    float se = 0.f;
#pragma unroll
    for (int k = 0; k < Kk; k++) {
        e[k] = __expf(sims[k] - mx);
        se += e[k];
    }
    float isum = 1.f / se;
#pragma unroll
    for (int k = 0; k < Kk; k++) wbuf[(size_t)n * Kk + k] = e[k] * isum;
}

// ---------------- K2: scatter w*f to msg (wave/point, lane=dim) -------------
__global__ __launch_bounds__(256) void k2_scatter(const float* __restrict__ f_pts,
                                                  const float* __restrict__ wbuf,
                                                  const int* __restrict__ cand,
                                                  float* __restrict__ msg,
                                                  float* __restrict__ wsum) {
    int wave = threadIdx.x >> 6;
    int lane = threadIdx.x & 63;
    int n = blockIdx.x * 4 + wave;          // grid = N/4 exactly
    float f = f_pts[(size_t)n * Dd + lane];
    int k8 = lane & 7;
    float wk = wbuf[(size_t)n * Kk + k8];
    int idxk = cand[(size_t)n * Kk + k8];
#pragma unroll
    for (int k = 0; k < Kk; k++) {
        float wv = __shfl(wk, k, 64);
        int id = __shfl(idxk, k, 64);
        atomicAdd(msg + (size_t)id * Dd + lane, wv * f);
    }
    if (lane < Kk) atomicAdd(wsum + idxk, wk);
}

// ---------------- K_pack: weights -> bf16 MFMA B-fragment layout ------------
// frag f, lane l: 8 bf16 = W[o = t*16 + (l&15)][k = c*32 + (l>>4)*8 + j]
// offsets (in frags): Wg1:0..7 (t*4+c) | W_ih:8..31 (t*2+c) | W_hh:32..55
//                     Wd1:56..67 | Wd2:68..85 (t*3+c)
__global__ __launch_bounds__(256) void k_pack(const float* __restrict__ Wg1,
                                              const float* __restrict__ W_ih,
                                              const float* __restrict__ W_hh,
                                              const float* __restrict__ Wd1,
                                              const float* __restrict__ Wd2,
                                              short* __restrict__ wsW) {
    int idx = blockIdx.x * 256 + threadIdx.x;
    if (idx >= 86 * 64) return;
    int f = idx >> 6, lane = idx & 63;
    int lrow = lane & 15, lhi = lane >> 4;
    const float* src;
    int t, c, K;
    if (f < 8)       { int g = f;      t = g >> 2; c = g & 3;  src = Wg1;  K = 128; }
    else if (f < 32) { int g = f - 8;  t = g >> 1; c = g & 1;  src = W_ih; K = 64; }
    else if (f < 56) { int g = f - 32; t = g >> 1; c = g & 1;  src = W_hh; K = 64; }
    else if (f < 68) { int g = f - 56; t = g >> 1; c = g & 1;  src = Wd1;  K = 64; }
    else             { int g = f - 68; t = g / 3;  c = g % 3;  src = Wd2;  K = 96; }
    int o = t * 16 + lrow;
    int k0 = c * 32 + lhi * 8;
    short* dst = wsW + ((size_t)f * 64 + lane) * 8;
#pragma unroll
    for (int j = 0; j < 8; j++) dst[j] = f2bf(src[(size_t)o * K + k0 + j]);
}

// ---------------- K3: MFMA voxel pipeline, wave per 16 voxels ---------------
__global__ __launch_bounds__(256) void k3_mfma(const float* __restrict__ z_latent,
                                               const float* __restrict__ msg,
                                               const float* __restrict__ wsum,
                                               const short* __restrict__ wsW,
                                               const float* __restrict__ bg1,
                                               const float* __restrict__ Wg2,
                                               const float* __restrict__ bg2,
                                               const float* __restrict__ b_ih,
                                               const float* __restrict__ b_hh,
                                               const float* __restrict__ ln_g,
                                               const float* __restrict__ ln_b,
                                               const float* __restrict__ bd1,
                                               const float* __restrict__ bd2,
                                               const float* __restrict__ Wd3,
                                               const float* __restrict__ bd3,
                                               const float* __restrict__ vacc,
                                               float* __restrict__ out) {
    __shared__ float scr_all[4][16 * 97];    // wave-private 16x97 stripes, 24.8 KB
    int wv = threadIdx.x >> 6, lane = threadIdx.x & 63;
    int tile = blockIdx.x * 4 + wv;
    if (tile >= Mm / 16) return;             // no barriers below -> safe early exit
    int m0 = tile * 16;
    float* scr = scr_all[wv];
    int lrow = lane & 15;                    // A/B operand row, D column
    int lhi = lane >> 4;                     // D row quad

    // vals passthrough (exact path)
    if (lane < 16) {
        float v = vacc[m0 + lane];
        out[Mm + m0 + lane] = fminf(fmaxf(v, -2.f), 3.5f);
    }

    // ---- A fragments: z, mg (16 rows x 64 K, 2 k-chunks each) ----
    bf16x8 za[2], ma[2];
    float minv = 1.f / (wsum[m0 + lrow] + 1e-6f);
    const float* zrow = z_latent + (size_t)(m0 + lrow) * Dd + lhi * 8;
    const float* mrow = msg + (size_t)(m0 + lrow) * Dd + lhi * 8;
#pragma unroll
    for (int c = 0; c < 2; c++) {
        bf16x8 t0, t1;
#pragma unroll
        for (int j = 0; j < 8; j++) {
            t0[j] = f2bf(zrow[c * 32 + j]);
            t1[j] = f2bf(mrow[c * 32 + j] * minv);
        }
        za[c] = t0; ma[c] = t1;
    }
    const bf16x8* WF = (const bf16x8*)wsW;
#define BFRAG(off) (WF[(off) * 64 + lane])

    // ---- gate: relu([z,mg]@Wg1.T+bg1)@Wg2.T+bg2 -> sigmoid ----
    f32x4 g0 = {0.f, 0.f, 0.f, 0.f}, g1 = {0.f, 0.f, 0.f, 0.f};
    bf16x8 gateA[4] = {za[0], za[1], ma[0], ma[1]};
#pragma unroll
    for (int c = 0; c < 4; c++) {
        g0 = __builtin_amdgcn_mfma_f32_16x16x32_bf16(gateA[c], BFRAG(0 + c), g0, 0, 0, 0);
        g1 = __builtin_amdgcn_mfma_f32_16x16x32_bf16(gateA[c], BFRAG(4 + c), g1, 0, 0, 0);
    }
    float bgA = bg1[lrow], bgB = bg1[16 + lrow];
    float w2A = Wg2[lrow], w2B = Wg2[16 + lrow];
    float g[4];
#pragma unroll
    for (int r = 0; r < 4; r++) {
        float ga = fmaxf(g0[r] + bgA, 0.f) * w2A + fmaxf(g1[r] + bgB, 0.f) * w2B;
        ga += __shfl_xor(ga, 1, 64);
        ga += __shfl_xor(ga, 2, 64);
        ga += __shfl_xor(ga, 4, 64);
        ga += __shfl_xor(ga, 8, 64);
        g[r] = sigmoidf_(ga + bg2[0]);
    }

    // ---- GRU: 12 col-tiles of 16 outs (r:0-3, z:4-7, n:8-11) ----
    float zn[4][4];                          // [t][r] z_new in C-layout
    float ps[4] = {0.f, 0.f, 0.f, 0.f}, pq[4] = {0.f, 0.f, 0.f, 0.f};
#pragma unroll
    for (int t = 0; t < 4; t++) {
        f32x4 Ar = {0.f, 0.f, 0.f, 0.f}, Az = Ar, An = Ar, Br = Ar, Bz = Ar, Bn = Ar;
#pragma unroll
        for (int c = 0; c < 2; c++) {
            Ar = __builtin_amdgcn_mfma_f32_16x16x32_bf16(ma[c], BFRAG(8 + t * 2 + c), Ar, 0, 0, 0);
            Az = __builtin_amdgcn_mfma_f32_16x16x32_bf16(ma[c], BFRAG(8 + (t + 4) * 2 + c), Az, 0, 0, 0);
            An = __builtin_amdgcn_mfma_f32_16x16x32_bf16(ma[c], BFRAG(8 + (t + 8) * 2 + c), An, 0, 0, 0);
            Br = __builtin_amdgcn_mfma_f32_16x16x32_bf16(za[c], BFRAG(32 + t * 2 + c), Br, 0, 0, 0);
            Bz = __builtin_amdgcn_mfma_f32_16x16x32_bf16(za[c], BFRAG(32 + (t + 4) * 2 + c), Bz, 0, 0, 0);
            Bn = __builtin_amdgcn_mfma_f32_16x16x32_bf16(za[c], BFRAG(32 + (t + 8) * 2 + c), Bn, 0, 0, 0);
        }
        int oc = t * 16 + lrow;
        float bir = b_ih[oc], biz = b_ih[64 + oc], bin = b_ih[128 + oc];
        float bhr = b_hh[oc], bhz = b_hh[64 + oc], bhn = b_hh[128 + oc];
#pragma unroll
        for (int r = 0; r < 4; r++) {
            int row = lhi * 4 + r;
            float zo = z_latent[(size_t)(m0 + row) * Dd + oc];
            float rr = sigmoidf_(Ar[r] + bir + Br[r] + bhr);
            float uu = sigmoidf_(Az[r] + biz + Bz[r] + bhz);
            float nnv = tanh_fast(An[r] + bin + rr * (Bn[r] + bhn));
            float hn = (1.f - uu) * nnv + uu * zo;
            float z2 = zo + g[r] * (hn - zo);
            zn[t][r] = z2;
            ps[r] += z2;
            pq[r] = fmaf(z2, z2, pq[r]);
        }
    }
    // LN stats: reduce over 64 cols (16-lane group x 4 tiles already in ps/pq)
    float mu[4], rs[4];
#pragma unroll
    for (int r = 0; r < 4; r++) {
        float s = ps[r], q = pq[r];
        s += __shfl_xor(s, 1, 64); q += __shfl_xor(q, 1, 64);
        s += __shfl_xor(s, 2, 64); q += __shfl_xor(q, 2, 64);
        s += __shfl_xor(s, 4, 64); q += __shfl_xor(q, 4, 64);
        s += __shfl_xor(s, 8, 64); q += __shfl_xor(q, 8, 64);
        float m = s * (1.f / 64.f);
        float v = q * (1.f / 64.f) - m * m;
        mu[r] = m;
        rs[r] = rsqrtf(v + 1e-5f);
    }
    // x = LN(z_new)  -> LDS (C-layout write, stride 97 = conflict-free)
#pragma unroll
    for (int t = 0; t < 4; t++) {
        int o = t * 16 + lrow;
        float lg = ln_g[o], lb = ln_b[o];
#pragma unroll
        for (int r = 0; r < 4; r++)
            scr[(lhi * 4 + r) * 97 + o] = (zn[t][r] - mu[r]) * rs[r] * lg + lb;
    }
    __threadfence_block();                   // cross-lane LDS visibility in-wave

    // x -> A-frags for fc1
    bf16x8 xa[2];
#pragma unroll
    for (int c = 0; c < 2; c++) {
        bf16x8 tb;
#pragma unroll
        for (int j = 0; j < 8; j++) tb[j] = f2bf(scr[lrow * 97 + c * 32 + lhi * 8 + j]);
        xa[c] = tb;
    }
    // fc1: 6 tiles x 2 chunks
    f32x4 h1t[6];
#pragma unroll
    for (int t = 0; t < 6; t++) h1t[t] = (f32x4){0.f, 0.f, 0.f, 0.f};
#pragma unroll
    for (int t = 0; t < 6; t++)
#pragma unroll
        for (int c = 0; c < 2; c++)
            h1t[t] = __builtin_amdgcn_mfma_f32_16x16x32_bf16(xa[c], BFRAG(56 + t * 2 + c), h1t[t], 0, 0, 0);
    float h1r[6][4];
#pragma unroll
    for (int t = 0; t < 6; t++) {
        float bb = bd1[t * 16 + lrow];
#pragma unroll
        for (int r = 0; r < 4; r++) {
            h1r[t][r] = fmaxf(h1t[t][r] + bb, 0.f);
            scr[(lhi * 4 + r) * 97 + t * 16 + lrow] = h1r[t][r];   // h1 -> LDS
        }
    }
    __threadfence_block();

    // h1 -> A-frags for fc2 (K=96, 3 chunks)
    bf16x8 ha[3];
#pragma unroll
    for (int c = 0; c < 3; c++) {
        bf16x8 tb;
#pragma unroll
        for (int j = 0; j < 8; j++) tb[j] = f2bf(scr[lrow * 97 + c * 32 + lhi * 8 + j]);
        ha[c] = tb;
    }
    // fc2 + residual + fc3
    f32x4 o2[6];
#pragma unroll
    for (int t = 0; t < 6; t++) o2[t] = (f32x4){0.f, 0.f, 0.f, 0.f};
#pragma unroll
    for (int t = 0; t < 6; t++)
#pragma unroll
        for (int c = 0; c < 3; c++)
            o2[t] = __builtin_amdgcn_mfma_f32_16x16x32_bf16(ha[c], BFRAG(68 + t * 3 + c), o2[t], 0, 0, 0);
    float pacc[4] = {0.f, 0.f, 0.f, 0.f};
#pragma unroll
    for (int t = 0; t < 6; t++) {
        int o = t * 16 + lrow;
        float bb = bd2[o], w3 = Wd3[o];
#pragma unroll
        for (int r = 0; r < 4; r++) {
            float hd2 = h1r[t][r] + fmaxf(o2[t][r] + bb, 0.f);
            pacc[r] = fmaf(hd2, w3, pacc[r]);
        }
    }
#pragma unroll
    for (int r = 0; r < 4; r++) {
        float s = pacc[r];
        s += __shfl_xor(s, 1, 64);
        s += __shfl_xor(s, 2, 64);
        s += __shfl_xor(s, 4, 64);
        s += __shfl_xor(s, 8, 64);
        if (lrow == 0) out[m0 + lhi * 4 + r] = sigmoidf_(s + bd3[0]);
    }
#undef BFRAG
}

extern "C" void kernel_launch(void* const* d_in, const int* in_sizes, int n_in,
                              void* d_out, int out_size, void* d_ws, size_t ws_size,
                              hipStream_t stream) {
    const float* pts      = (const float*)d_in[0];
    const float* f_pts    = (const float*)d_in[1];
    const float* z_lat    = (const float*)d_in[2];
    const float* vals     = (const float*)d_in[3];
    const float* centers  = (const float*)d_in[4];
    const float* Wf       = (const float*)d_in[5];
    const float* Wz       = (const float*)d_in[6];
    const float* w_delta  = (const float*)d_in[7];
    const float* b_delta  = (const float*)d_in[8];
    const float* log_temp = (const float*)d_in[9];
    const float* W_ih     = (const float*)d_in[10];
    const float* W_hh     = (const float*)d_in[11];
    const float* b_ih     = (const float*)d_in[12];
    const float* b_hh     = (const float*)d_in[13];
    const float* Wg1      = (const float*)d_in[14];
    const float* bg1      = (const float*)d_in[15];
    const float* Wg2      = (const float*)d_in[16];
    const float* bg2      = (const float*)d_in[17];
    const float* ln_g     = (const float*)d_in[18];
    const float* ln_b     = (const float*)d_in[19];
    const float* Wd1      = (const float*)d_in[20];
    const float* bd1      = (const float*)d_in[21];
    const float* Wd2      = (const float*)d_in[22];
    const float* bd2      = (const float*)d_in[23];
    const float* Wd3      = (const float*)d_in[24];
    const float* bd3      = (const float*)d_in[25];
    const int*   keys     = (const int*)d_in[26];
    const int*   cand     = (const int*)d_in[27];
    float* out = (float*)d_out;

    float* ws   = (float*)d_ws;
    float* Zall = ws;                            // M*16 (dead after k1; reused for wsW)
    float* wbuf = Zall + (size_t)Mm * Pp;        // N*8
    float* msg  = wbuf + (size_t)Nn * Kk;        // M*64
    float* wsum = msg + (size_t)Mm * Dd;         // M
    float* vacc = wsum + Mm;                     // M   (total ~36.6 MB)
    short* wsW  = (short*)Zall;                  // 86 frags * 64 lanes * 16 B = 88 KB

    hipMemsetAsync(msg, 0, sizeof(float) * ((size_t)Mm * Dd + Mm), stream);
    hipMemcpyAsync(vacc, vals, sizeof(float) * Mm, hipMemcpyDeviceToDevice, stream);

    k0_projz<<<(Mm + 255) / 256, 256, 0, stream>>>(z_lat, Wz, Zall);
    k1_route<<<(Nn + 255) / 256, 256, 0, stream>>>(pts, f_pts, centers, Wf, w_delta,
                                                   b_delta, log_temp, keys, cand,
                                                   Zall, wbuf, vacc);
    // pack AFTER k1: wsW aliases Zall
    k_pack<<<(86 * 64 + 255) / 256, 256, 0, stream>>>(Wg1, W_ih, W_hh, Wd1, Wd2, wsW);
    k2_scatter<<<Nn / 4, 256, 0, stream>>>(f_pts, wbuf, cand, msg, wsum);
    k3_mfma<<<(Mm / 16 + 3) / 4, 256, 0, stream>>>(z_lat, msg, wsum, wsW, bg1, Wg2, bg2,
                                                   b_ih, b_hh, ln_g, ln_b, bd1, bd2,
                                                   Wd3, bd3, vacc, out);
}

// Round 3
// 388.163 us; speedup vs baseline: 3.3821x; 1.3360x over previous
//
#include <hip/hip_runtime.h>
#include <math.h>

#define Nn 120000
#define Kk 8
#define Dd 64
#define Mm 100000
#define Pp 16
#define HGg 32
#define HDd 96
#define CAP 48   // per-voxel bucket capacity; Poisson(9.6) max ~31, P(>=48)~1e-23

typedef __attribute__((ext_vector_type(8))) short bf16x8;
typedef __attribute__((ext_vector_type(4))) float f32x4;

__device__ __forceinline__ float sigmoidf_(float x) { return 1.f / (1.f + __expf(-x)); }
__device__ __forceinline__ float tanh_fast(float x) {
    float e = __expf(2.f * x);          // inf for big x -> 1; 0 for very neg -> -1
    return 1.f - 2.f / (e + 1.f);
}
// f32 -> bf16 round-to-nearest-even
__device__ __forceinline__ short f2bf(float f) {
    unsigned u = __float_as_uint(f);
    unsigned r = (u + 0x7fffu + ((u >> 16) & 1u)) >> 16;
    return (short)r;
}

// ---------------- K0: Zall[m] = normalize(z_latent[m] @ Wz.T)  (M,16) -------
__global__ __launch_bounds__(256) void k0_projz(const float* __restrict__ z,
                                                const float* __restrict__ Wz,
                                                float* __restrict__ Zall) {
    int m = blockIdx.x * 256 + threadIdx.x;
    if (m >= Mm) return;
    const float4* zr = (const float4*)(z + (size_t)m * Dd);
    float acc[Pp];
#pragma unroll
    for (int p = 0; p < Pp; p++) acc[p] = 0.f;
    for (int d4 = 0; d4 < 16; ++d4) {
        float4 f4 = zr[d4];
#pragma unroll
        for (int p = 0; p < Pp; p++) {
            const float* w = Wz + p * Dd + d4 * 4;   // wave-uniform -> s_load
            acc[p] = fmaf(f4.x, w[0], acc[p]);
            acc[p] = fmaf(f4.y, w[1], acc[p]);
            acc[p] = fmaf(f4.z, w[2], acc[p]);
            acc[p] = fmaf(f4.w, w[3], acc[p]);
        }
    }
    float ss = 0.f;
#pragma unroll
    for (int p = 0; p < Pp; p++) ss = fmaf(acc[p], acc[p], ss);
    float inv = 1.f / (sqrtf(ss) + 1e-6f);
    float4* o = (float4*)(Zall + (size_t)m * Pp);
#pragma unroll
    for (int q = 0; q < 4; q++) {
        float4 v;
        v.x = acc[4 * q] * inv;
        v.y = acc[4 * q + 1] * inv;
        v.z = acc[4 * q + 2] * inv;
        v.w = acc[4 * q + 3] * inv;
        o[q] = v;
    }
}

// --- K1: hash+searchsorted+vals atomic; routing softmax; bucket insert ------
__global__ __launch_bounds__(256) void k1_route(const float* __restrict__ pts,
                                                const float* __restrict__ f_pts,
                                                const float* __restrict__ centers,
                                                const float* __restrict__ Wf,
                                                const float* __restrict__ w_delta,
                                                const float* __restrict__ b_delta,
                                                const float* __restrict__ log_temp,
                                                const int* __restrict__ keys,
                                                const int* __restrict__ cand,
                                                const float* __restrict__ Zall,
                                                float* __restrict__ wbuf,
                                                float* __restrict__ vacc,
                                                int* __restrict__ cnt,
                                                int* __restrict__ rec) {
    int n = blockIdx.x * 256 + threadIdx.x;
    if (n >= Nn) return;
    float px = pts[3 * n], py = pts[3 * n + 1], pz = pts[3 * n + 2];
    // IEEE f32 divide then floor, matching the reference exactly (boundary-sensitive)
    int ix = (int)floorf(px / 0.1f);
    int iy = (int)floorf(py / 0.1f);
    int iz = (int)floorf(pz / 0.1f);
    int h = ((ix + 512) << 20) ^ ((iy + 512) << 10) ^ (iz + 512);
    // lower_bound (searchsorted side='left')
    int lo = 0, hi = Mm;
    while (lo < hi) {
        int mid = (lo + hi) >> 1;
        if (keys[mid] < h) lo = mid + 1; else hi = mid;
    }
    int vi = lo < (Mm - 1) ? lo : (Mm - 1);
    atomicAdd(vacc + vi, 0.5f);

    // Fp = normalize(f_pts[n] @ Wf.T)
    float acc[Pp];
#pragma unroll
    for (int p = 0; p < Pp; p++) acc[p] = 0.f;
    const float4* fr = (const float4*)(f_pts + (size_t)n * Dd);
    for (int d4 = 0; d4 < 16; ++d4) {
        float4 f4 = fr[d4];
#pragma unroll
        for (int p = 0; p < Pp; p++) {
            const float* w = Wf + p * Dd + d4 * 4;
            acc[p] = fmaf(f4.x, w[0], acc[p]);
            acc[p] = fmaf(f4.y, w[1], acc[p]);
            acc[p] = fmaf(f4.z, w[2], acc[p]);
            acc[p] = fmaf(f4.w, w[3], acc[p]);
        }
    }
    float ss = 0.f;
#pragma unroll
    for (int p = 0; p < Pp; p++) ss = fmaf(acc[p], acc[p], ss);
    float inv = 1.f / (sqrtf(ss) + 1e-6f);
#pragma unroll
    for (int p = 0; p < Pp; p++) acc[p] *= inv;

    float et = expf(log_temp[0]);
    float wdx = w_delta[0], wdy = w_delta[1], wdz = w_delta[2], bdl = b_delta[0];
    float sims[Kk];
    int ids[Kk];
#pragma unroll
    for (int k = 0; k < Kk; k++) {
        int id = cand[(size_t)n * Kk + k];
        ids[k] = id;
        const float4* zp = (const float4*)(Zall + (size_t)id * Pp);
        float core = 0.f;
#pragma unroll
        for (int q = 0; q < 4; q++) {
            float4 zv = zp[q];
            core = fmaf(acc[4 * q], zv.x, core);
            core = fmaf(acc[4 * q + 1], zv.y, core);
            core = fmaf(acc[4 * q + 2], zv.z, core);
            core = fmaf(acc[4 * q + 3], zv.w, core);
        }
        float cx = centers[3 * id], cy = centers[3 * id + 1], cz = centers[3 * id + 2];
        float dt = (px - cx) * wdx + (py - cy) * wdy + (pz - cz) * wdz + bdl;
        sims[k] = et * (core + dt);
    }
    float mx = -1e30f;
#pragma unroll
    for (int k = 0; k < Kk; k++) {
        sims[k] = sims[k] / 0.3f;
        mx = fmaxf(mx, sims[k]);
    }
    float e[Kk];
    float se = 0.f;
#pragma unroll
    for (int k = 0; k < Kk; k++) {
        e[k] = __expf(sims[k] - mx);
        se += e[k];
    }
    float isum = 1.f / se;
#pragma unroll
    for (int k = 0; k < Kk; k++) {
        float wv = e[k] * isum;
        wbuf[(size_t)n * Kk + k] = wv;
        int v = ids[k];
        int pos = atomicAdd(cnt + v, 1);
        if (pos < CAP) rec[(size_t)v * CAP + pos] = (n << 3) | k;
    }
}

// ---- K2: gather-reduce per voxel (wave/voxel, lane=dim); fused wsum norm ---
__global__ __launch_bounds__(256) void k2_reduce(const float* __restrict__ f_pts,
                                                 const float* __restrict__ wbuf,
                                                 const int* __restrict__ cnt,
                                                 const int* __restrict__ rec,
                                                 float* __restrict__ msg) {
    int wv = threadIdx.x >> 6, lane = threadIdx.x & 63;
    int m = blockIdx.x * 4 + wv;
    if (m >= Mm) return;
    int c = cnt[m];
    if (c > CAP) c = CAP;
    const int4* r4 = (const int4*)(rec + (size_t)m * CAP);
    float a0 = 0.f, a1 = 0.f, a2 = 0.f, a3 = 0.f;
    float w0 = 0.f, w1 = 0.f, w2 = 0.f, w3 = 0.f;
    for (int i0 = 0; i0 < c; i0 += 4) {
        int4 e = r4[i0 >> 2];              // wave-uniform record quad
        // guards are wave-uniform (c, e uniform) -> no divergence
        if (i0 + 0 < c) { float w = wbuf[e.x]; w0 += w; a0 = fmaf(w, f_pts[(size_t)(e.x >> 3) * Dd + lane], a0); }
        if (i0 + 1 < c) { float w = wbuf[e.y]; w1 += w; a1 = fmaf(w, f_pts[(size_t)(e.y >> 3) * Dd + lane], a1); }
        if (i0 + 2 < c) { float w = wbuf[e.z]; w2 += w; a2 = fmaf(w, f_pts[(size_t)(e.z >> 3) * Dd + lane], a2); }
        if (i0 + 3 < c) { float w = wbuf[e.w]; w3 += w; a3 = fmaf(w, f_pts[(size_t)(e.w >> 3) * Dd + lane], a3); }
    }
    float acc = (a0 + a1) + (a2 + a3);
    float wsum = (w0 + w1) + (w2 + w3);
    msg[(size_t)m * Dd + lane] = acc / (wsum + 1e-6f);   // pre-normalized msg
}

// ---------------- K_pack: weights -> bf16 MFMA B-fragment layout ------------
// frag f, lane l: 8 bf16 = W[o = t*16 + (l&15)][k = c*32 + (l>>4)*8 + j]
__global__ __launch_bounds__(256) void k_pack(const float* __restrict__ Wg1,
                                              const float* __restrict__ W_ih,
                                              const float* __restrict__ W_hh,
                                              const float* __restrict__ Wd1,
                                              const float* __restrict__ Wd2,
                                              short* __restrict__ wsW) {
    int idx = blockIdx.x * 256 + threadIdx.x;
    if (idx >= 86 * 64) return;
    int f = idx >> 6, lane = idx & 63;
    int lrow = lane & 15, lhi = lane >> 4;
    const float* src;
    int t, c, K;
    if (f < 8)       { int g = f;      t = g >> 2; c = g & 3;  src = Wg1;  K = 128; }
    else if (f < 32) { int g = f - 8;  t = g >> 1; c = g & 1;  src = W_ih; K = 64; }
    else if (f < 56) { int g = f - 32; t = g >> 1; c = g & 1;  src = W_hh; K = 64; }
    else if (f < 68) { int g = f - 56; t = g >> 1; c = g & 1;  src = Wd1;  K = 64; }
    else             { int g = f - 68; t = g / 3;  c = g % 3;  src = Wd2;  K = 96; }
    int o = t * 16 + lrow;
    int k0 = c * 32 + lhi * 8;
    short* dst = wsW + ((size_t)f * 64 + lane) * 8;
#pragma unroll
    for (int j = 0; j < 8; j++) dst[j] = f2bf(src[(size_t)o * K + k0 + j]);
}

// ---------------- K3: MFMA voxel pipeline, wave per 16 voxels ---------------
__global__ __launch_bounds__(256) void k3_mfma(const float* __restrict__ z_latent,
                                               const float* __restrict__ msg,
                                               const short* __restrict__ wsW,
                                               const float* __restrict__ bg1,
                                               const float* __restrict__ Wg2,
                                               const float* __restrict__ bg2,
                                               const float* __restrict__ b_ih,
                                               const float* __restrict__ b_hh,
                                               const float* __restrict__ ln_g,
                                               const float* __restrict__ ln_b,
                                               const float* __restrict__ bd1,
                                               const float* __restrict__ bd2,
                                               const float* __restrict__ Wd3,
                                               const float* __restrict__ bd3,
                                               const float* __restrict__ vacc,
                                               float* __restrict__ out) {
    __shared__ float scr_all[4][16 * 97];    // wave-private 16x97 stripes, 24.8 KB
    int wv = threadIdx.x >> 6, lane = threadIdx.x & 63;
    int tile = blockIdx.x * 4 + wv;
    if (tile >= Mm / 16) return;             // no barriers below -> safe early exit
    int m0 = tile * 16;
    float* scr = scr_all[wv];
    int lrow = lane & 15;                    // A/B operand row, D column
    int lhi = lane >> 4;                     // D row quad

    // vals passthrough (exact path)
    if (lane < 16) {
        float v = vacc[m0 + lane];
        out[Mm + m0 + lane] = fminf(fmaxf(v, -2.f), 3.5f);
    }

    // ---- A fragments: z, mg (16 rows x 64 K, 2 k-chunks each) ----
    bf16x8 za[2], ma[2];
    const float* zrow = z_latent + (size_t)(m0 + lrow) * Dd + lhi * 8;
    const float* mrow = msg + (size_t)(m0 + lrow) * Dd + lhi * 8;   // pre-normalized
#pragma unroll
    for (int c = 0; c < 2; c++) {
        bf16x8 t0, t1;
#pragma unroll
        for (int j = 0; j < 8; j++) {
            t0[j] = f2bf(zrow[c * 32 + j]);
            t1[j] = f2bf(mrow[c * 32 + j]);
        }
        za[c] = t0; ma[c] = t1;
    }
    const bf16x8* WF = (const bf16x8*)wsW;
#define BFRAG(off) (WF[(off) * 64 + lane])

    // ---- gate: relu([z,mg]@Wg1.T+bg1)@Wg2.T+bg2 -> sigmoid ----
    f32x4 g0 = {0.f, 0.f, 0.f, 0.f}, g1 = {0.f, 0.f, 0.f, 0.f};
    bf16x8 gateA[4] = {za[0], za[1], ma[0], ma[1]};
#pragma unroll
    for (int c = 0; c < 4; c++) {
        g0 = __builtin_amdgcn_mfma_f32_16x16x32_bf16(gateA[c], BFRAG(0 + c), g0, 0, 0, 0);
        g1 = __builtin_amdgcn_mfma_f32_16x16x32_bf16(gateA[c], BFRAG(4 + c), g1, 0, 0, 0);
    }
    float bgA = bg1[lrow], bgB = bg1[16 + lrow];
    float w2A = Wg2[lrow], w2B = Wg2[16 + lrow];
    float g[4];
#pragma unroll
    for (int r = 0; r < 4; r++) {
        float ga = fmaxf(g0[r] + bgA, 0.f) * w2A + fmaxf(g1[r] + bgB, 0.f) * w2B;
        ga += __shfl_xor(ga, 1, 64);
        ga += __shfl_xor(ga, 2, 64);
        ga += __shfl_xor(ga, 4, 64);
        ga += __shfl_xor(ga, 8, 64);
        g[r] = sigmoidf_(ga + bg2[0]);
    }

    // ---- GRU: 12 col-tiles of 16 outs (r:0-3, z:4-7, n:8-11) ----
    float zn[4][4];                          // [t][r] z_new in C-layout
    float ps[4] = {0.f, 0.f, 0.f, 0.f}, pq[4] = {0.f, 0.f, 0.f, 0.f};
#pragma unroll
    for (int t = 0; t < 4; t++) {
        f32x4 Ar = {0.f, 0.f, 0.f, 0.f}, Az = Ar, An = Ar, Br = Ar, Bz = Ar, Bn = Ar;
#pragma unroll
        for (int c = 0; c < 2; c++) {
            Ar = __builtin_amdgcn_mfma_f32_16x16x32_bf16(ma[c], BFRAG(8 + t * 2 + c), Ar, 0, 0, 0);
            Az = __builtin_amdgcn_mfma_f32_16x16x32_bf16(ma[c], BFRAG(8 + (t + 4) * 2 + c), Az, 0, 0, 0);
            An = __builtin_amdgcn_mfma_f32_16x16x32_bf16(ma[c], BFRAG(8 + (t + 8) * 2 + c), An, 0, 0, 0);
            Br = __builtin_amdgcn_mfma_f32_16x16x32_bf16(za[c], BFRAG(32 + t * 2 + c), Br, 0, 0, 0);
            Bz = __builtin_amdgcn_mfma_f32_16x16x32_bf16(za[c], BFRAG(32 + (t + 4) * 2 + c), Bz, 0, 0, 0);
            Bn = __builtin_amdgcn_mfma_f32_16x16x32_bf16(za[c], BFRAG(32 + (t + 8) * 2 + c), Bn, 0, 0, 0);
        }
        int oc = t * 16 + lrow;
        float bir = b_ih[oc], biz = b_ih[64 + oc], bin = b_ih[128 + oc];
        float bhr = b_hh[oc], bhz = b_hh[64 + oc], bhn = b_hh[128 + oc];
#pragma unroll
        for (int r = 0; r < 4; r++) {
            int row = lhi * 4 + r;
            float zo = z_latent[(size_t)(m0 + row) * Dd + oc];
            float rr = sigmoidf_(Ar[r] + bir + Br[r] + bhr);
            float uu = sigmoidf_(Az[r] + biz + Bz[r] + bhz);
            float nnv = tanh_fast(An[r] + bin + rr * (Bn[r] + bhn));
            float hn = (1.f - uu) * nnv + uu * zo;
            float z2 = zo + g[r] * (hn - zo);
            zn[t][r] = z2;
            ps[r] += z2;
            pq[r] = fmaf(z2, z2, pq[r]);
        }
    }
    // LN stats: reduce over 64 cols
    float mu[4], rs[4];
#pragma unroll
    for (int r = 0; r < 4; r++) {
        float s = ps[r], q = pq[r];
        s += __shfl_xor(s, 1, 64); q += __shfl_xor(q, 1, 64);
        s += __shfl_xor(s, 2, 64); q += __shfl_xor(q, 2, 64);
        s += __shfl_xor(s, 4, 64); q += __shfl_xor(q, 4, 64);
        s += __shfl_xor(s, 8, 64); q += __shfl_xor(q, 8, 64);
        float m = s * (1.f / 64.f);
        float v = q * (1.f / 64.f) - m * m;
        mu[r] = m;
        rs[r] = rsqrtf(v + 1e-5f);
    }
    // x = LN(z_new)  -> LDS (C-layout write, stride 97 = conflict-free)
#pragma unroll
    for (int t = 0; t < 4; t++) {
        int o = t * 16 + lrow;
        float lg = ln_g[o], lb = ln_b[o];
#pragma unroll
        for (int r = 0; r < 4; r++)
            scr[(lhi * 4 + r) * 97 + o] = (zn[t][r] - mu[r]) * rs[r] * lg + lb;
    }
    __threadfence_block();                   // cross-lane LDS visibility in-wave

    // x -> A-frags for fc1
    bf16x8 xa[2];
#pragma unroll
    for (int c = 0; c < 2; c++) {
        bf16x8 tb;
#pragma unroll
        for (int j = 0; j < 8; j++) tb[j] = f2bf(scr[lrow * 97 + c * 32 + lhi * 8 + j]);
        xa[c] = tb;
    }
    // fc1: 6 tiles x 2 chunks
    f32x4 h1t[6];
#pragma unroll
    for (int t = 0; t < 6; t++) h1t[t] = (f32x4){0.f, 0.f, 0.f, 0.f};
#pragma unroll
    for (int t = 0; t < 6; t++)
#pragma unroll
        for (int c = 0; c < 2; c++)
            h1t[t] = __builtin_amdgcn_mfma_f32_16x16x32_bf16(xa[c], BFRAG(56 + t * 2 + c), h1t[t], 0, 0, 0);
    float h1r[6][4];
#pragma unroll
    for (int t = 0; t < 6; t++) {
        float bb = bd1[t * 16 + lrow];
#pragma unroll
        for (int r = 0; r < 4; r++) {
            h1r[t][r] = fmaxf(h1t[t][r] + bb, 0.f);
            scr[(lhi * 4 + r) * 97 + t * 16 + lrow] = h1r[t][r];   // h1 -> LDS
        }
    }
    __threadfence_block();

    // h1 -> A-frags for fc2 (K=96, 3 chunks)
    bf16x8 ha[3];
#pragma unroll
    for (int c = 0; c < 3; c++) {
        bf16x8 tb;
#pragma unroll
        for (int j = 0; j < 8; j++) tb[j] = f2bf(scr[lrow * 97 + c * 32 + lhi * 8 + j]);
        ha[c] = tb;
    }
    // fc2 + residual + fc3
    f32x4 o2[6];
#pragma unroll
    for (int t = 0; t < 6; t++) o2[t] = (f32x4){0.f, 0.f, 0.f, 0.f};
#pragma unroll
    for (int t = 0; t < 6; t++)
#pragma unroll
        for (int c = 0; c < 3; c++)
            o2[t] = __builtin_amdgcn_mfma_f32_16x16x32_bf16(ha[c], BFRAG(68 + t * 3 + c), o2[t], 0, 0, 0);
    float pacc[4] = {0.f, 0.f, 0.f, 0.f};
#pragma unroll
    for (int t = 0; t < 6; t++) {
        int o = t * 16 + lrow;
        float bb = bd2[o], w3 = Wd3[o];
#pragma unroll
        for (int r = 0; r < 4; r++) {
            float hd2 = h1r[t][r] + fmaxf(o2[t][r] + bb, 0.f);
            pacc[r] = fmaf(hd2, w3, pacc[r]);
        }
    }
#pragma unroll
    for (int r = 0; r < 4; r++) {
        float s = pacc[r];
        s += __shfl_xor(s, 1, 64);
        s += __shfl_xor(s, 2, 64);
        s += __shfl_xor(s, 4, 64);
        s += __shfl_xor(s, 8, 64);
        if (lrow == 0) out[m0 + lhi * 4 + r] = sigmoidf_(s + bd3[0]);
    }
#undef BFRAG
}

extern "C" void kernel_launch(void* const* d_in, const int* in_sizes, int n_in,
                              void* d_out, int out_size, void* d_ws, size_t ws_size,
                              hipStream_t stream) {
    const float* pts      = (const float*)d_in[0];
    const float* f_pts    = (const float*)d_in[1];
    const float* z_lat    = (const float*)d_in[2];
    const float* vals     = (const float*)d_in[3];
    const float* centers  = (const float*)d_in[4];
    const float* Wf       = (const float*)d_in[5];
    const float* Wz       = (const float*)d_in[6];
    const float* w_delta  = (const float*)d_in[7];
    const float* b_delta  = (const float*)d_in[8];
    const float* log_temp = (const float*)d_in[9];
    const float* W_ih     = (const float*)d_in[10];
    const float* W_hh     = (const float*)d_in[11];
    const float* b_ih     = (const float*)d_in[12];
    const float* b_hh     = (const float*)d_in[13];
    const float* Wg1      = (const float*)d_in[14];
    const float* bg1      = (const float*)d_in[15];
    const float* Wg2      = (const float*)d_in[16];
    const float* bg2      = (const float*)d_in[17];
    const float* ln_g     = (const float*)d_in[18];
    const float* ln_b     = (const float*)d_in[19];
    const float* Wd1      = (const float*)d_in[20];
    const float* bd1      = (const float*)d_in[21];
    const float* Wd2      = (const float*)d_in[22];
    const float* bd2      = (const float*)d_in[23];
    const float* Wd3      = (const float*)d_in[24];
    const float* bd3      = (const float*)d_in[25];
    const int*   keys     = (const int*)d_in[26];
    const int*   cand     = (const int*)d_in[27];
    float* out = (float*)d_out;

    float* ws   = (float*)d_ws;
    float* Zall = ws;                            // M*16 f32; dead after k1 -> wsW aliases
    float* wbuf = Zall + (size_t)Mm * Pp;        // N*8
    float* msg  = wbuf + (size_t)Nn * Kk;        // M*64 (written once by k2_reduce)
    float* vacc = msg + (size_t)Mm * Dd;         // M
    int*   cnt  = (int*)(vacc + Mm);             // M
    int*   rec  = cnt + Mm;                      // M*CAP  (total ~55.8 MB)
    short* wsW  = (short*)Zall;                  // 86 frags * 64 lanes * 16 B = 88 KB

    hipMemsetAsync(cnt, 0, sizeof(int) * Mm, stream);
    hipMemcpyAsync(vacc, vals, sizeof(float) * Mm, hipMemcpyDeviceToDevice, stream);

    k0_projz<<<(Mm + 255) / 256, 256, 0, stream>>>(z_lat, Wz, Zall);
    k1_route<<<(Nn + 255) / 256, 256, 0, stream>>>(pts, f_pts, centers, Wf, w_delta,
                                                   b_delta, log_temp, keys, cand,
                                                   Zall, wbuf, vacc, cnt, rec);
    // pack AFTER k1: wsW aliases Zall
    k_pack<<<(86 * 64 + 255) / 256, 256, 0, stream>>>(Wg1, W_ih, W_hh, Wd1, Wd2, wsW);
    k2_reduce<<<(Mm + 3) / 4, 256, 0, stream>>>(f_pts, wbuf, cnt, rec, msg);
    k3_mfma<<<(Mm / 16 + 3) / 4, 256, 0, stream>>>(z_lat, msg, wsW, bg1, Wg2, bg2,
                                                   b_ih, b_hh, ln_g, ln_b, bd1, bd2,
                                                   Wd3, bd3, vacc, out);
}

// Round 4
// 384.800 us; speedup vs baseline: 3.4116x; 1.0087x over previous
//
#include <hip/hip_runtime.h>
#include <math.h>

#define Nn 120000
#define Kk 8
#define Dd 64
#define Mm 100000
#define Pp 16
#define HGg 32
#define HDd 96
#define CAP 48   // per-voxel bucket capacity; Poisson(9.6) max ~31, P(>=48)~1e-23

typedef __attribute__((ext_vector_type(8))) short bf16x8;
typedef __attribute__((ext_vector_type(4))) float f32x4;

__device__ __forceinline__ float sigmoidf_(float x) { return 1.f / (1.f + __expf(-x)); }
__device__ __forceinline__ float tanh_fast(float x) {
    float e = __expf(2.f * x);          // inf for big x -> 1; 0 for very neg -> -1
    return 1.f - 2.f / (e + 1.f);
}
// f32 -> bf16 round-to-nearest-even
__device__ __forceinline__ short f2bf(float f) {
    unsigned u = __float_as_uint(f);
    unsigned r = (u + 0x7fffu + ((u >> 16) & 1u)) >> 16;
    return (short)r;
}

// -------- K0: Zall[m] = normalize(z_latent[m] @ Wz.T); cdot[m] = c[m].w ----
__global__ __launch_bounds__(256) void k0_projz(const float* __restrict__ z,
                                                const float* __restrict__ Wz,
                                                const float* __restrict__ centers,
                                                const float* __restrict__ w_delta,
                                                float* __restrict__ Zall,
                                                float* __restrict__ cdot) {
    int m = blockIdx.x * 256 + threadIdx.x;
    if (m >= Mm) return;
    const float4* zr = (const float4*)(z + (size_t)m * Dd);
    float acc[Pp];
#pragma unroll
    for (int p = 0; p < Pp; p++) acc[p] = 0.f;
    for (int d4 = 0; d4 < 16; ++d4) {
        float4 f4 = zr[d4];
#pragma unroll
        for (int p = 0; p < Pp; p++) {
            const float* w = Wz + p * Dd + d4 * 4;   // wave-uniform -> s_load
            acc[p] = fmaf(f4.x, w[0], acc[p]);
            acc[p] = fmaf(f4.y, w[1], acc[p]);
            acc[p] = fmaf(f4.z, w[2], acc[p]);
            acc[p] = fmaf(f4.w, w[3], acc[p]);
        }
    }
    float ss = 0.f;
#pragma unroll
    for (int p = 0; p < Pp; p++) ss = fmaf(acc[p], acc[p], ss);
    float inv = 1.f / (sqrtf(ss) + 1e-6f);
    float4* o = (float4*)(Zall + (size_t)m * Pp);
#pragma unroll
    for (int q = 0; q < 4; q++) {
        float4 v;
        v.x = acc[4 * q] * inv;
        v.y = acc[4 * q + 1] * inv;
        v.z = acc[4 * q + 2] * inv;
        v.w = acc[4 * q + 3] * inv;
        o[q] = v;
    }
    // cdot: dot(centers[m], w_delta)  (p-c).w+b == p.w - cdot + b
    cdot[m] = centers[3 * m] * w_delta[0] + centers[3 * m + 1] * w_delta[1]
            + centers[3 * m + 2] * w_delta[2];
}

// --- K1: 4 lanes per point. hash+search+vacc; Fp via group-split dots;
//         2 candidates per lane; group softmax; bucket insert. -------------
__global__ __launch_bounds__(256) void k1_route(const float* __restrict__ pts,
                                                const float* __restrict__ f_pts,
                                                const float* __restrict__ Wf,
                                                const float* __restrict__ w_delta,
                                                const float* __restrict__ b_delta,
                                                const float* __restrict__ log_temp,
                                                const int* __restrict__ keys,
                                                const int* __restrict__ cand,
                                                const float* __restrict__ Zall,
                                                const float* __restrict__ cdot,
                                                float* __restrict__ wbuf,
                                                float* __restrict__ vacc,
                                                int* __restrict__ cnt,
                                                int* __restrict__ rec) {
    int g = threadIdx.x & 3;                         // lane-in-group
    int n = blockIdx.x * 64 + (threadIdx.x >> 2);    // grid = 1875 exact

    float px = pts[3 * n], py = pts[3 * n + 1], pz = pts[3 * n + 2];

    // candidate ids early (ILP): lane handles k = 2g, 2g+1
    int2 myid = ((const int2*)(cand + (size_t)n * Kk))[g];

    // IEEE f32 divide then floor, matching the reference exactly
    int ix = (int)floorf(px / 0.1f);
    int iy = (int)floorf(py / 0.1f);
    int iz = (int)floorf(pz / 0.1f);
    int h = ((ix + 512) << 20) ^ ((iy + 512) << 10) ^ (iz + 512);
    // lower_bound; redundant across the 4 lanes (same addresses -> broadcast)
    int lo = 0, hi = Mm;
    while (lo < hi) {
        int mid = (lo + hi) >> 1;
        if (keys[mid] < h) lo = mid + 1; else hi = mid;
    }
    int vi = lo < (Mm - 1) ? lo : (Mm - 1);
    if (g == 0) atomicAdd(vacc + vi, 0.5f);

    // ---- Fp partial dots over this lane's 16-float quarter ----
    const float4* fr = (const float4*)(f_pts + (size_t)n * Dd + g * 16);
    float4 q0 = fr[0], q1 = fr[1], q2 = fr[2], q3 = fr[3];
    float fp[Pp];
#pragma unroll
    for (int p = 0; p < Pp; p++) {
        const float4* w = (const float4*)(Wf + (size_t)p * Dd + g * 16);
        float4 w0 = w[0], w1 = w[1], w2 = w[2], w3 = w[3];
        float s = q0.x * w0.x + q0.y * w0.y + q0.z * w0.z + q0.w * w0.w;
        s += q1.x * w1.x + q1.y * w1.y + q1.z * w1.z + q1.w * w1.w;
        s += q2.x * w2.x + q2.y * w2.y + q2.z * w2.z + q2.w * w2.w;
        s += q3.x * w3.x + q3.y * w3.y + q3.z * w3.z + q3.w * w3.w;
        fp[p] = s;
    }
    // group-reduce: every lane gets the full 16-dim projection
#pragma unroll
    for (int p = 0; p < Pp; p++) {
        fp[p] += __shfl_xor(fp[p], 1, 64);
        fp[p] += __shfl_xor(fp[p], 2, 64);
    }
    float ss = 0.f;
#pragma unroll
    for (int p = 0; p < Pp; p++) ss = fmaf(fp[p], fp[p], ss);
    float inv = 1.f / (sqrtf(ss) + 1e-6f);
#pragma unroll
    for (int p = 0; p < Pp; p++) fp[p] *= inv;

    float et = expf(log_temp[0]);
    float pdot = px * w_delta[0] + py * w_delta[1] + pz * w_delta[2] + b_delta[0];

    // ---- this lane's 2 candidates ----
    int ids[2] = {myid.x, myid.y};
    float sims[2];
#pragma unroll
    for (int t = 0; t < 2; t++) {
        int id = ids[t];
        const float4* zp = (const float4*)(Zall + (size_t)id * Pp);
        float4 z0 = zp[0], z1 = zp[1], z2 = zp[2], z3 = zp[3];
        float core = fp[0] * z0.x + fp[1] * z0.y + fp[2] * z0.z + fp[3] * z0.w;
        core += fp[4] * z1.x + fp[5] * z1.y + fp[6] * z1.z + fp[7] * z1.w;
        core += fp[8] * z2.x + fp[9] * z2.y + fp[10] * z2.z + fp[11] * z2.w;
        core += fp[12] * z3.x + fp[13] * z3.y + fp[14] * z3.z + fp[15] * z3.w;
        float dt = pdot - cdot[id];
        sims[t] = et * (core + dt) / 0.3f;
    }
    // softmax over the 8 sims spread 2/lane across the 4-lane group
    float mx = fmaxf(sims[0], sims[1]);
    mx = fmaxf(mx, __shfl_xor(mx, 1, 64));
    mx = fmaxf(mx, __shfl_xor(mx, 2, 64));
    float e0 = __expf(sims[0] - mx), e1 = __expf(sims[1] - mx);
    float se = e0 + e1;
    se += __shfl_xor(se, 1, 64);
    se += __shfl_xor(se, 2, 64);
    float isum = 1.f / se;
    float w0 = e0 * isum, w1 = e1 * isum;
    ((float2*)(wbuf + (size_t)n * Kk))[g] = make_float2(w0, w1);

    // bucket insert (2 per lane)
    int p0 = atomicAdd(cnt + ids[0], 1);
    if (p0 < CAP) rec[(size_t)ids[0] * CAP + p0] = (n << 3) | (2 * g);
    int p1 = atomicAdd(cnt + ids[1], 1);
    if (p1 < CAP) rec[(size_t)ids[1] * CAP + p1] = (n << 3) | (2 * g + 1);
}

// ---- K2: gather-reduce per voxel (wave/voxel, lane=dim); fused wsum norm ---
__global__ __launch_bounds__(256) void k2_reduce(const float* __restrict__ f_pts,
                                                 const float* __restrict__ wbuf,
                                                 const int* __restrict__ cnt,
                                                 const int* __restrict__ rec,
                                                 float* __restrict__ msg) {
    int wv = threadIdx.x >> 6, lane = threadIdx.x & 63;
    int m = blockIdx.x * 4 + wv;
    if (m >= Mm) return;
    int c = cnt[m];
    if (c > CAP) c = CAP;
    const int4* r4 = (const int4*)(rec + (size_t)m * CAP);
    float a0 = 0.f, a1 = 0.f, a2 = 0.f, a3 = 0.f;
    float w0 = 0.f, w1 = 0.f, w2 = 0.f, w3 = 0.f;
    for (int i0 = 0; i0 < c; i0 += 4) {
        int4 e = r4[i0 >> 2];              // wave-uniform record quad
        if (i0 + 0 < c) { float w = wbuf[e.x]; w0 += w; a0 = fmaf(w, f_pts[(size_t)(e.x >> 3) * Dd + lane], a0); }
        if (i0 + 1 < c) { float w = wbuf[e.y]; w1 += w; a1 = fmaf(w, f_pts[(size_t)(e.y >> 3) * Dd + lane], a1); }
        if (i0 + 2 < c) { float w = wbuf[e.z]; w2 += w; a2 = fmaf(w, f_pts[(size_t)(e.z >> 3) * Dd + lane], a2); }
        if (i0 + 3 < c) { float w = wbuf[e.w]; w3 += w; a3 = fmaf(w, f_pts[(size_t)(e.w >> 3) * Dd + lane], a3); }
    }
    float acc = (a0 + a1) + (a2 + a3);
    float wsum = (w0 + w1) + (w2 + w3);
    msg[(size_t)m * Dd + lane] = acc / (wsum + 1e-6f);   // pre-normalized msg
}

// ---------------- K_pack: weights -> bf16 MFMA B-fragment layout ------------
// frag f, lane l: 8 bf16 = W[o = t*16 + (l&15)][k = c*32 + (l>>4)*8 + j]
__global__ __launch_bounds__(256) void k_pack(const float* __restrict__ Wg1,
                                              const float* __restrict__ W_ih,
                                              const float* __restrict__ W_hh,
                                              const float* __restrict__ Wd1,
                                              const float* __restrict__ Wd2,
                                              short* __restrict__ wsW) {
    int idx = blockIdx.x * 256 + threadIdx.x;
    if (idx >= 86 * 64) return;
    int f = idx >> 6, lane = idx & 63;
    int lrow = lane & 15, lhi = lane >> 4;
    const float* src;
    int t, c, K;
    if (f < 8)       { int g = f;      t = g >> 2; c = g & 3;  src = Wg1;  K = 128; }
    else if (f < 32) { int g = f - 8;  t = g >> 1; c = g & 1;  src = W_ih; K = 64; }
    else if (f < 56) { int g = f - 32; t = g >> 1; c = g & 1;  src = W_hh; K = 64; }
    else if (f < 68) { int g = f - 56; t = g >> 1; c = g & 1;  src = Wd1;  K = 64; }
    else             { int g = f - 68; t = g / 3;  c = g % 3;  src = Wd2;  K = 96; }
    int o = t * 16 + lrow;
    int k0 = c * 32 + lhi * 8;
    short* dst = wsW + ((size_t)f * 64 + lane) * 8;
#pragma unroll
    for (int j = 0; j < 8; j++) dst[j] = f2bf(src[(size_t)o * K + k0 + j]);
}

// ---------------- K3: MFMA voxel pipeline, wave per 16 voxels ---------------
__global__ __launch_bounds__(256) void k3_mfma(const float* __restrict__ z_latent,
                                               const float* __restrict__ msg,
                                               const short* __restrict__ wsW,
                                               const float* __restrict__ bg1,
                                               const float* __restrict__ Wg2,
                                               const float* __restrict__ bg2,
                                               const float* __restrict__ b_ih,
                                               const float* __restrict__ b_hh,
                                               const float* __restrict__ ln_g,
                                               const float* __restrict__ ln_b,
                                               const float* __restrict__ bd1,
                                               const float* __restrict__ bd2,
                                               const float* __restrict__ Wd3,
                                               const float* __restrict__ bd3,
                                               const float* __restrict__ vacc,
                                               float* __restrict__ out) {
    __shared__ float scr_all[4][16 * 97];    // wave-private 16x97 stripes, 24.8 KB
    int wv = threadIdx.x >> 6, lane = threadIdx.x & 63;
    int tile = blockIdx.x * 4 + wv;
    if (tile >= Mm / 16) return;             // no barriers below -> safe early exit
    int m0 = tile * 16;
    float* scr = scr_all[wv];
    int lrow = lane & 15;                    // A/B operand row, D column
    int lhi = lane >> 4;                     // D row quad

    // vals passthrough (exact path)
    if (lane < 16) {
        float v = vacc[m0 + lane];
        out[Mm + m0 + lane] = fminf(fmaxf(v, -2.f), 3.5f);
    }

    // ---- A fragments: z, mg (16 rows x 64 K, 2 k-chunks each) ----
    bf16x8 za[2], ma[2];
    const float* zrow = z_latent + (size_t)(m0 + lrow) * Dd + lhi * 8;
    const float* mrow = msg + (size_t)(m0 + lrow) * Dd + lhi * 8;   // pre-normalized
#pragma unroll
    for (int c = 0; c < 2; c++) {
        bf16x8 t0, t1;
#pragma unroll
        for (int j = 0; j < 8; j++) {
            t0[j] = f2bf(zrow[c * 32 + j]);
            t1[j] = f2bf(mrow[c * 32 + j]);
        }
        za[c] = t0; ma[c] = t1;
    }
    const bf16x8* WF = (const bf16x8*)wsW;
#define BFRAG(off) (WF[(off) * 64 + lane])

    // ---- gate: relu([z,mg]@Wg1.T+bg1)@Wg2.T+bg2 -> sigmoid ----
    f32x4 g0 = {0.f, 0.f, 0.f, 0.f}, g1 = {0.f, 0.f, 0.f, 0.f};
    bf16x8 gateA[4] = {za[0], za[1], ma[0], ma[1]};
#pragma unroll
    for (int c = 0; c < 4; c++) {
        g0 = __builtin_amdgcn_mfma_f32_16x16x32_bf16(gateA[c], BFRAG(0 + c), g0, 0, 0, 0);
        g1 = __builtin_amdgcn_mfma_f32_16x16x32_bf16(gateA[c], BFRAG(4 + c), g1, 0, 0, 0);
    }
    float bgA = bg1[lrow], bgB = bg1[16 + lrow];
    float w2A = Wg2[lrow], w2B = Wg2[16 + lrow];
    float g[4];
#pragma unroll
    for (int r = 0; r < 4; r++) {
        float ga = fmaxf(g0[r] + bgA, 0.f) * w2A + fmaxf(g1[r] + bgB, 0.f) * w2B;
        ga += __shfl_xor(ga, 1, 64);
        ga += __shfl_xor(ga, 2, 64);
        ga += __shfl_xor(ga, 4, 64);
        ga += __shfl_xor(ga, 8, 64);
        g[r] = sigmoidf_(ga + bg2[0]);
    }

    // ---- GRU: 12 col-tiles of 16 outs (r:0-3, z:4-7, n:8-11) ----
    float zn[4][4];                          // [t][r] z_new in C-layout
    float ps[4] = {0.f, 0.f, 0.f, 0.f}, pq[4] = {0.f, 0.f, 0.f, 0.f};
#pragma unroll
    for (int t = 0; t < 4; t++) {
        f32x4 Ar = {0.f, 0.f, 0.f, 0.f}, Az = Ar, An = Ar, Br = Ar, Bz = Ar, Bn = Ar;
#pragma unroll
        for (int c = 0; c < 2; c++) {
            Ar = __builtin_amdgcn_mfma_f32_16x16x32_bf16(ma[c], BFRAG(8 + t * 2 + c), Ar, 0, 0, 0);
            Az = __builtin_amdgcn_mfma_f32_16x16x32_bf16(ma[c], BFRAG(8 + (t + 4) * 2 + c), Az, 0, 0, 0);
            An = __builtin_amdgcn_mfma_f32_16x16x32_bf16(ma[c], BFRAG(8 + (t + 8) * 2 + c), An, 0, 0, 0);
            Br = __builtin_amdgcn_mfma_f32_16x16x32_bf16(za[c], BFRAG(32 + t * 2 + c), Br, 0, 0, 0);
            Bz = __builtin_amdgcn_mfma_f32_16x16x32_bf16(za[c], BFRAG(32 + (t + 4) * 2 + c), Bz, 0, 0, 0);
            Bn = __builtin_amdgcn_mfma_f32_16x16x32_bf16(za[c], BFRAG(32 + (t + 8) * 2 + c), Bn, 0, 0, 0);
        }
        int oc = t * 16 + lrow;
        float bir = b_ih[oc], biz = b_ih[64 + oc], bin = b_ih[128 + oc];
        float bhr = b_hh[oc], bhz = b_hh[64 + oc], bhn = b_hh[128 + oc];
#pragma unroll
        for (int r = 0; r < 4; r++) {
            int row = lhi * 4 + r;
            float zo = z_latent[(size_t)(m0 + row) * Dd + oc];
            float rr = sigmoidf_(Ar[r] + bir + Br[r] + bhr);
            float uu = sigmoidf_(Az[r] + biz + Bz[r] + bhz);
            float nnv = tanh_fast(An[r] + bin + rr * (Bn[r] + bhn));
            float hn = (1.f - uu) * nnv + uu * zo;
            float z2 = zo + g[r] * (hn - zo);
            zn[t][r] = z2;
            ps[r] += z2;
            pq[r] = fmaf(z2, z2, pq[r]);
        }
    }
    // LN stats: reduce over 64 cols
    float mu[4], rs[4];
#pragma unroll
    for (int r = 0; r < 4; r++) {
        float s = ps[r], q = pq[r];
        s += __shfl_xor(s, 1, 64); q += __shfl_xor(q, 1, 64);
        s += __shfl_xor(s, 2, 64); q += __shfl_xor(q, 2, 64);
        s += __shfl_xor(s, 4, 64); q += __shfl_xor(q, 4, 64);
        s += __shfl_xor(s, 8, 64); q += __shfl_xor(q, 8, 64);
        float m = s * (1.f / 64.f);
        float v = q * (1.f / 64.f) - m * m;
        mu[r] = m;
        rs[r] = rsqrtf(v + 1e-5f);
    }
    // x = LN(z_new)  -> LDS (C-layout write, stride 97 = conflict-free)
#pragma unroll
    for (int t = 0; t < 4; t++) {
        int o = t * 16 + lrow;
        float lg = ln_g[o], lb = ln_b[o];
#pragma unroll
        for (int r = 0; r < 4; r++)
            scr[(lhi * 4 + r) * 97 + o] = (zn[t][r] - mu[r]) * rs[r] * lg + lb;
    }
    __threadfence_block();                   // cross-lane LDS visibility in-wave

    // x -> A-frags for fc1
    bf16x8 xa[2];
#pragma unroll
    for (int c = 0; c < 2; c++) {
        bf16x8 tb;
#pragma unroll
        for (int j = 0; j < 8; j++) tb[j] = f2bf(scr[lrow * 97 + c * 32 + lhi * 8 + j]);
        xa[c] = tb;
    }
    // fc1: 6 tiles x 2 chunks
    f32x4 h1t[6];
#pragma unroll
    for (int t = 0; t < 6; t++) h1t[t] = (f32x4){0.f, 0.f, 0.f, 0.f};
#pragma unroll
    for (int t = 0; t < 6; t++)
#pragma unroll
        for (int c = 0; c < 2; c++)
            h1t[t] = __builtin_amdgcn_mfma_f32_16x16x32_bf16(xa[c], BFRAG(56 + t * 2 + c), h1t[t], 0, 0, 0);
    float h1r[6][4];
#pragma unroll
    for (int t = 0; t < 6; t++) {
        float bb = bd1[t * 16 + lrow];
#pragma unroll
        for (int r = 0; r < 4; r++) {
            h1r[t][r] = fmaxf(h1t[t][r] + bb, 0.f);
            scr[(lhi * 4 + r) * 97 + t * 16 + lrow] = h1r[t][r];   // h1 -> LDS
        }
    }
    __threadfence_block();

    // h1 -> A-frags for fc2 (K=96, 3 chunks)
    bf16x8 ha[3];
#pragma unroll
    for (int c = 0; c < 3; c++) {
        bf16x8 tb;
#pragma unroll
        for (int j = 0; j < 8; j++) tb[j] = f2bf(scr[lrow * 97 + c * 32 + lhi * 8 + j]);
        ha[c] = tb;
    }
    // fc2 + residual + fc3
    f32x4 o2[6];
#pragma unroll
    for (int t = 0; t < 6; t++) o2[t] = (f32x4){0.f, 0.f, 0.f, 0.f};
#pragma unroll
    for (int t = 0; t < 6; t++)
#pragma unroll
        for (int c = 0; c < 3; c++)
            o2[t] = __builtin_amdgcn_mfma_f32_16x16x32_bf16(ha[c], BFRAG(68 + t * 3 + c), o2[t], 0, 0, 0);
    float pacc[4] = {0.f, 0.f, 0.f, 0.f};
#pragma unroll
    for (int t = 0; t < 6; t++) {
        int o = t * 16 + lrow;
        float bb = bd2[o], w3 = Wd3[o];
#pragma unroll
        for (int r = 0; r < 4; r++) {
            float hd2 = h1r[t][r] + fmaxf(o2[t][r] + bb, 0.f);
            pacc[r] = fmaf(hd2, w3, pacc[r]);
        }
    }
#pragma unroll
    for (int r = 0; r < 4; r++) {
        float s = pacc[r];
        s += __shfl_xor(s, 1, 64);
        s += __shfl_xor(s, 2, 64);
        s += __shfl_xor(s, 4, 64);
        s += __shfl_xor(s, 8, 64);
        if (lrow == 0) out[m0 + lhi * 4 + r] = sigmoidf_(s + bd3[0]);
    }
#undef BFRAG
}

extern "C" void kernel_launch(void* const* d_in, const int* in_sizes, int n_in,
                              void* d_out, int out_size, void* d_ws, size_t ws_size,
                              hipStream_t stream) {
    const float* pts      = (const float*)d_in[0];
    const float* f_pts    = (const float*)d_in[1];
    const float* z_lat    = (const float*)d_in[2];
    const float* vals     = (const float*)d_in[3];
    const float* centers  = (const float*)d_in[4];
    const float* Wf       = (const float*)d_in[5];
    const float* Wz       = (const float*)d_in[6];
    const float* w_delta  = (const float*)d_in[7];
    const float* b_delta  = (const float*)d_in[8];
    const float* log_temp = (const float*)d_in[9];
    const float* W_ih     = (const float*)d_in[10];
    const float* W_hh     = (const float*)d_in[11];
    const float* b_ih     = (const float*)d_in[12];
    const float* b_hh     = (const float*)d_in[13];
    const float* Wg1      = (const float*)d_in[14];
    const float* bg1      = (const float*)d_in[15];
    const float* Wg2      = (const float*)d_in[16];
    const float* bg2      = (const float*)d_in[17];
    const float* ln_g     = (const float*)d_in[18];
    const float* ln_b     = (const float*)d_in[19];
    const float* Wd1      = (const float*)d_in[20];
    const float* bd1      = (const float*)d_in[21];
    const float* Wd2      = (const float*)d_in[22];
    const float* bd2      = (const float*)d_in[23];
    const float* Wd3      = (const float*)d_in[24];
    const float* bd3      = (const float*)d_in[25];
    const int*   keys     = (const int*)d_in[26];
    const int*   cand     = (const int*)d_in[27];
    float* out = (float*)d_out;

    float* ws   = (float*)d_ws;
    float* Zall = ws;                            // M*16 f32; dead after k1 -> wsW aliases
    float* wbuf = Zall + (size_t)Mm * Pp;        // N*8
    float* msg  = wbuf + (size_t)Nn * Kk;        // M*64 (written once by k2_reduce)
    float* vacc = msg + (size_t)Mm * Dd;         // M
    int*   cnt  = (int*)(vacc + Mm);             // M
    int*   rec  = cnt + Mm;                      // M*CAP
    float* cdot = (float*)(rec + (size_t)Mm * CAP);  // M  (total ~56.2 MB)
    short* wsW  = (short*)Zall;                  // 86 frags * 64 lanes * 16 B = 88 KB

    hipMemsetAsync(cnt, 0, sizeof(int) * Mm, stream);
    hipMemcpyAsync(vacc, vals, sizeof(float) * Mm, hipMemcpyDeviceToDevice, stream);

    k0_projz<<<(Mm + 255) / 256, 256, 0, stream>>>(z_lat, Wz, centers, w_delta, Zall, cdot);
    k1_route<<<Nn / 64, 256, 0, stream>>>(pts, f_pts, Wf, w_delta, b_delta, log_temp,
                                          keys, cand, Zall, cdot, wbuf, vacc, cnt, rec);
    // pack AFTER k1: wsW aliases Zall
    k_pack<<<(86 * 64 + 255) / 256, 256, 0, stream>>>(Wg1, W_ih, W_hh, Wd1, Wd2, wsW);
    k2_reduce<<<(Mm + 3) / 4, 256, 0, stream>>>(f_pts, wbuf, cnt, rec, msg);
    k3_mfma<<<(Mm / 16 + 3) / 4, 256, 0, stream>>>(z_lat, msg, wsW, bg1, Wg2, bg2,
                                                   b_ih, b_hh, ln_g, ln_b, bd1, bd2,
                                                   Wd3, bd3, vacc, out);
}